// Round 21
// baseline (34.772 us; speedup 1.0000x reference)
//
#include <hip/hip_runtime.h>
#include <hip/hip_bf16.h>

#define BDIM 512

typedef __attribute__((ext_vector_type(8))) _Float16 f16x8;
typedef __attribute__((ext_vector_type(4))) _Float16 f16x4;
typedef __attribute__((ext_vector_type(4))) float f32x4;

// native v_exp_f32 computes 2^x; __exp2f doesn't exist in HIP
#define EXP2F(x) __builtin_amdgcn_exp2f(x)

// Local windowed attention with RoPE. b=32, n=4096, d=64, WINDOW=128, 1 backward window.
// ONE BLOCK PER WINDOW-PAIR (RoPE relative-position invariance -> middle K/V half
// shared; block-common origin, t in [0,384)). 3 halves in 2 rolling LDS slots
// (72.7KB, 2 blocks/CU, launch_bounds(512,4)).
// R21 = R20 (31.9us) + two latency cuts:
//  - XCD-CHUNKED BLOCK SWIZZLE: 512 blocks = 8 XCDs x 64; default round-robin puts
//    neighbor pairs (which share a boundary K/V half) on different XCDs -> shared
//    half filled into two L2s from L3. Chunk map z = (x&7)*64 + x>>3 (bijective)
//    gives each XCD 64 consecutive (bb,wp) -> shared halves become L2 hits.
//  - K-STAGING SINCOS RECURRENCE: it=1 rows have t+64, so cos/sin derive from it=0
//    via 4 precomputed (cos,sin)(64*invf) pairs: 8 fma replace 4 sincos, x3 phases.
// Carried from R20: front-staging load/convert split (all 20 float4 in flight),
// swapped QK^T via mfma(K,Q) (stats c-layout, accO row-layout, 1/s shuffled c->row),
// permuted Vt columns (PV B = one ds_read_b128), flat softmax over acc[16], fused
// exp/pack/PV, exp2-domain scores, tile-granular causal skips, diag mask 4g+r > c.
// Spill sentinel: WRITE_SIZE == output 32.8MB.
__global__ __launch_bounds__(512, 4)
void la_kernel(const float* __restrict__ qg, const float* __restrict__ kg,
               const float* __restrict__ vg, float* __restrict__ outg)
{
    __shared__ _Float16 Ks[2][128][72];   // 36864 B
    __shared__ _Float16 Vt[2][64][140];   // 35840 B   total 72704 B

    // XCD-chunked swizzle: XCD = blockIdx.x % 8 (default RR); give each XCD a
    // contiguous chunk of 64 logical blocks so neighbor pairs share its L2.
    const int z  = ((blockIdx.x & 7) << 6) | (blockIdx.x >> 3);
    const int wp = z & 15, bb = z >> 4;

    const int tid = threadIdx.x;
    const int wv = tid >> 6, lane = tid & 63, g = lane >> 4, c = lane & 15;
    const int base = 256 * wp - 128;      // phys row of t=0 (block-common origin)
    const float NEG = -3.0e38f;
    const float NLT32 = -0.28782313662425572f;   // -ln(10000)/32
    const float QSCALE = 0.125f * 1.4426950408889634f;  // d^-0.5 * log2(e)
    const size_t rowb = (size_t)bb * 4096;

    // hoisted inverse frequencies + 64-step rotation constants for K recurrence
    const int cbK = (tid & 7) << 2;
    float invfK[4], c64[4], s64[4];
    #pragma unroll
    for (int u = 0; u < 4; ++u) {
        invfK[u] = __expf((float)(cbK + u) * NLT32);
        __sincosf(64.0f * invfK[u], &s64[u], &c64[u]);
    }
    float invfQ[8];
    #pragma unroll
    for (int u = 0; u < 8; ++u) invfQ[u] = __expf((float)(8 * g + u) * NLT32);

    const int jqV = tid >> 4, eqV = tid & 15;
    const int colbV = ((jqV & 24) << 2) + 8 * (jqV & 3) + 4 * ((jqV >> 2) & 1);

    const int qrow = wv * 16 + c;

    // ---- staging split: raw loads / convert+LDS-write ----
    auto stageLoad = [&](int mm, float4* kx, float4* vx) {
        #pragma unroll
        for (int it = 0; it < 2; ++it) {
            int j = (tid + it * 512) >> 3;         // 0..127
            const float* p = kg + (rowb + base + 128 * mm + j) * 64 + cbK;
            kx[2 * it]     = *(const float4*)p;
            kx[2 * it + 1] = *(const float4*)(p + 32);
        }
        #pragma unroll
        for (int w = 0; w < 4; ++w)
            vx[w] = *(const float4*)(vg + (rowb + base + 128 * mm + 4 * jqV + w) * 64 + 4 * eqV);
    };
    auto stageConv = [&](int mm, const float4* kx, const float4* vx) {
        const int sl = mm & 1;
        float csA[4], snA[4];
        #pragma unroll
        for (int it = 0; it < 2; ++it) {
            int j = (tid + it * 512) >> 3;
            int t = 128 * mm + j;
            const float* x1p = (const float*)&kx[2 * it];
            const float* x2p = (const float*)&kx[2 * it + 1];
            f16x4 lo, hi;
            #pragma unroll
            for (int u = 0; u < 4; ++u) {
                float sn, cs;
                if (it == 0) {
                    __sincosf((float)t * invfK[u], &sn, &cs);
                    csA[u] = cs; snA[u] = sn;
                } else {
                    // t -> t+64 rotation (angle addition; 1 extra f32 rounding step)
                    cs = csA[u] * c64[u] - snA[u] * s64[u];
                    sn = snA[u] * c64[u] + csA[u] * s64[u];
                }
                lo[u] = (_Float16)(x1p[u] * cs - x2p[u] * sn);
                hi[u] = (_Float16)(x2p[u] * cs + x1p[u] * sn);
            }
            *(f16x4*)&Ks[sl][j][cbK]      = lo;
            *(f16x4*)&Ks[sl][j][cbK + 32] = hi;
        }
        #pragma unroll
        for (int u = 0; u < 4; ++u) {
            f16x4 o;
            o[0] = (_Float16)((const float*)&vx[0])[u];
            o[1] = (_Float16)((const float*)&vx[1])[u];
            o[2] = (_Float16)((const float*)&vx[2])[u];
            o[3] = (_Float16)((const float*)&vx[3])[u];
            *(f16x4*)&Vt[sl][4 * eqV + u][colbV] = o;
        }
    };
    auto stageFused = [&](int mm) {       // for stage(2): load+convert in one pass
        float4 kx[4], vx[4];
        stageLoad(mm, kx, vx);
        stageConv(mm, kx, vx);
    };

    // ---- Q: split load / RoPE ----
    auto loadQraw = [&](int wi, float4* qr) {
        const int tq = 128 * (wi + 1) + qrow;
        const float* p = qg + (rowb + base + tq) * 64 + 8 * g;
        qr[0] = *(const float4*)p;
        qr[1] = *(const float4*)(p + 4);
        qr[2] = *(const float4*)(p + 32);
        qr[3] = *(const float4*)(p + 36);
    };
    auto ropeQ = [&](int wi, const float4* qr, f16x8& qa0, f16x8& qa1) {
        const int tq = 128 * (wi + 1) + qrow;
        float ra[8] = {qr[0].x,qr[0].y,qr[0].z,qr[0].w,qr[1].x,qr[1].y,qr[1].z,qr[1].w};
        float rb[8] = {qr[2].x,qr[2].y,qr[2].z,qr[2].w,qr[3].x,qr[3].y,qr[3].z,qr[3].w};
        #pragma unroll
        for (int u = 0; u < 8; ++u) {
            float sn, cs; __sincosf((float)tq * invfQ[u], &sn, &cs);
            float a = ra[u] * QSCALE, b = rb[u] * QSCALE;
            qa0[u] = (_Float16)(a * cs - b * sn);
            qa1[u] = (_Float16)(b * cs + a * sn);
        }
    };

    // ---- compute one window (wi), flat softmax, fused exp+pack+PV ----
    auto computeWin = [&](int wi, f16x8 qa0, f16x8 qa1) {
        const bool skipFirst = (wp == 0 && wi == 0);  // padding half
        const int sl0 = wi & 1, sl1 = (wi + 1) & 1;
        const f32x4 CZERO = (f32x4){0.f, 0.f, 0.f, 0.f};

        f32x4 acc[16];
        #pragma unroll
        for (int jt = 0; jt < 16; ++jt) {
            const bool doit = (jt < 8) ? (!skipFirst) : ((jt - 8) <= wv);
            if (doit) {
                const int sl = (jt < 8) ? sl0 : sl1;
                const int row = (jt & 7) * 16 + c;
                f16x8 kb0 = *(const f16x8*)&Ks[sl][row][8 * g];
                f16x8 kb1 = *(const f16x8*)&Ks[sl][row][32 + 8 * g];
                acc[jt] = __builtin_amdgcn_mfma_f32_16x16x32_f16(kb0, qa0, CZERO, 0, 0, 0);
                acc[jt] = __builtin_amdgcn_mfma_f32_16x16x32_f16(kb1, qa1, acc[jt], 0, 0, 0);
            }
        }

        // mask (diag tile only) + max over computed tiles
        float mx = NEG;
        #pragma unroll
        for (int jt = 0; jt < 16; ++jt) {
            const bool doit = (jt < 8) ? (!skipFirst) : ((jt - 8) <= wv);
            if (doit) {
                if (jt >= 8 && jt == 8 + wv) {
                    #pragma unroll
                    for (int r = 0; r < 4; ++r)
                        if (4 * g + r > c) acc[jt][r] = NEG;
                }
                #pragma unroll
                for (int r = 0; r < 4; ++r) mx = fmaxf(mx, acc[jt][r]);
            }
        }
        mx = fmaxf(mx, __shfl_xor(mx, 16));
        mx = fmaxf(mx, __shfl_xor(mx, 32));

        // fused: per 32-key group, exp2 + pack ONE fragment + 4 PV MFMAs; s on the fly
        f32x4 accO[4];
        #pragma unroll
        for (int nt = 0; nt < 4; ++nt) accO[nt] = CZERO;

        float s = 0.f;
        #pragma unroll
        for (int st = 0; st < 8; ++st) {
            const bool grp = (st < 4) ? (!skipFirst) : ((2 * st - 8) <= wv);
            if (grp) {
                f16x8 pa;
                #pragma unroll
                for (int r = 0; r < 4; ++r) {
                    float p = EXP2F(acc[2 * st][r] - mx);     // masked -> 0
                    s += p;
                    pa[r] = (_Float16)p;
                }
                const bool oddOk = (st < 4) || ((2 * st - 7) <= wv);
                if (oddOk) {
                    #pragma unroll
                    for (int r = 0; r < 4; ++r) {
                        float p = EXP2F(acc[2 * st + 1][r] - mx);
                        s += p;
                        pa[4 + r] = (_Float16)p;
                    }
                } else {
                    #pragma unroll
                    for (int r = 0; r < 4; ++r) pa[4 + r] = (_Float16)0.f;
                }
                const int sl = (st < 4) ? sl0 : sl1;
                #pragma unroll
                for (int nt = 0; nt < 4; ++nt) {
                    f16x8 vb = *(const f16x8*)&Vt[sl][nt * 16 + c][(st & 3) * 32 + 8 * g];
                    accO[nt] = __builtin_amdgcn_mfma_f32_16x16x32_f16(pa, vb, accO[nt], 0, 0, 0);
                }
            }
        }
        s += __shfl_xor(s, 16);
        s += __shfl_xor(s, 32);

        // epilogue: 1/s (c-layout) -> row-layout, store
        float rcp = 1.0f / s;
        float rcpD[4];
        #pragma unroll
        for (int r = 0; r < 4; ++r)
            rcpD[r] = __shfl(rcp, (lane & 48) | (4 * g + r));

        float* op = outg + (rowb + base + 128 * (wi + 1) + wv * 16) * 64;
        #pragma unroll
        for (int nt = 0; nt < 4; ++nt)
            #pragma unroll
            for (int r = 0; r < 4; ++r)
                op[(size_t)(4 * g + r) * 64 + nt * 16 + c] = accO[nt][r] * rcpD[r];
    };

    // ---- schedule: issue ALL front loads (Q, K0, V0, K1, V1) -> convert both ->
    //      ropeQ(0) -> sync -> win0 -> Qraw(1) -> sync -> stage(2) fused ->
    //      ropeQ(1) -> sync -> win1 ----
    float4 qr[4];
    loadQraw(0, qr);
    float4 k0[4], v0[4], k1[4], v1[4];
    if (wp > 0) stageLoad(0, k0, v0);
    stageLoad(1, k1, v1);
    if (wp > 0) stageConv(0, k0, v0);
    stageConv(1, k1, v1);

    f16x8 qA, qB;
    ropeQ(0, qr, qA, qB);
    __syncthreads();
    computeWin(0, qA, qB);
    loadQraw(1, qr);                      // issue win1's Q before the barrier
    __syncthreads();                      // all reads of slot0 done
    stageFused(2);
    ropeQ(1, qr, qA, qB);
    __syncthreads();
    computeWin(1, qA, qB);
}

extern "C" void kernel_launch(void* const* d_in, const int* in_sizes, int n_in,
                              void* d_out, int out_size, void* d_ws, size_t ws_size,
                              hipStream_t stream) {
    (void)in_sizes; (void)n_in; (void)out_size; (void)d_ws; (void)ws_size;
    const float* q = (const float*)d_in[0];
    const float* k = (const float*)d_in[1];
    const float* v = (const float*)d_in[2];
    float* out = (float*)d_out;
    la_kernel<<<dim3(512), BDIM, 0, stream>>>(q, k, v, out);
}

// Round 22
// 34.323 us; speedup vs baseline: 1.0131x; 1.0131x over previous
//
#include <hip/hip_runtime.h>
#include <hip/hip_bf16.h>

#define BDIM 512

typedef __attribute__((ext_vector_type(8))) _Float16 f16x8;
typedef __attribute__((ext_vector_type(4))) _Float16 f16x4;
typedef __attribute__((ext_vector_type(4))) float f32x4;

// native v_exp_f32 computes 2^x; __exp2f doesn't exist in HIP
#define EXP2F(x) __builtin_amdgcn_exp2f(x)

// Local windowed attention with RoPE. b=32, n=4096, d=64, WINDOW=128, 1 backward window.
// ONE BLOCK PER WINDOW-PAIR (RoPE relative-position invariance -> middle K/V half
// shared; block-common origin, t in [0,384)). 3 halves in 2 rolling LDS slots
// (72.7KB, 2 blocks/CU, launch_bounds(512,4)).
// R22 = R20 (31.9us) + K-staging sincos recurrence ONLY. R21 bundled this with an
// XCD swizzle and regressed (34.8us, FETCH/WRITE both crept); the swizzle is reverted
// (grid back to natural (wp,bb) dim3(16,32)). This round isolates the recurrence:
// VALU savings (VALUBusy 19->16.5 measured in R21) vs its register cost.
// Decision rule: WRITE>33.5MB or dur>=32.5 -> net-negative, R20 is final.
// Carried from R20: front-staging load/convert split (all 20 float4 in flight),
// swapped QK^T via mfma(K,Q) (stats c-layout, accO row-layout, 1/s shuffled c->row),
// permuted Vt columns (PV B = one ds_read_b128), flat softmax over acc[16], fused
// exp/pack/PV, exp2-domain scores, tile-granular causal skips, diag mask 4g+r > c.
// Spill sentinel: WRITE_SIZE == output 32.8MB.
__global__ __launch_bounds__(512, 4)
void la_kernel(const float* __restrict__ qg, const float* __restrict__ kg,
               const float* __restrict__ vg, float* __restrict__ outg)
{
    __shared__ _Float16 Ks[2][128][72];   // 36864 B
    __shared__ _Float16 Vt[2][64][140];   // 35840 B   total 72704 B

    const int wp = blockIdx.x, bb = blockIdx.y;
    const int tid = threadIdx.x;
    const int wv = tid >> 6, lane = tid & 63, g = lane >> 4, c = lane & 15;
    const int base = 256 * wp - 128;      // phys row of t=0 (block-common origin)
    const float NEG = -3.0e38f;
    const float NLT32 = -0.28782313662425572f;   // -ln(10000)/32
    const float QSCALE = 0.125f * 1.4426950408889634f;  // d^-0.5 * log2(e)
    const size_t rowb = (size_t)bb * 4096;

    // hoisted inverse frequencies + 64-step rotation constants for K recurrence
    const int cbK = (tid & 7) << 2;
    float invfK[4], c64[4], s64[4];
    #pragma unroll
    for (int u = 0; u < 4; ++u) {
        invfK[u] = __expf((float)(cbK + u) * NLT32);
        __sincosf(64.0f * invfK[u], &s64[u], &c64[u]);
    }
    float invfQ[8];
    #pragma unroll
    for (int u = 0; u < 8; ++u) invfQ[u] = __expf((float)(8 * g + u) * NLT32);

    const int jqV = tid >> 4, eqV = tid & 15;
    const int colbV = ((jqV & 24) << 2) + 8 * (jqV & 3) + 4 * ((jqV >> 2) & 1);

    const int qrow = wv * 16 + c;

    // ---- staging split: raw loads / convert+LDS-write ----
    auto stageLoad = [&](int mm, float4* kx, float4* vx) {
        #pragma unroll
        for (int it = 0; it < 2; ++it) {
            int j = (tid + it * 512) >> 3;         // 0..127
            const float* p = kg + (rowb + base + 128 * mm + j) * 64 + cbK;
            kx[2 * it]     = *(const float4*)p;
            kx[2 * it + 1] = *(const float4*)(p + 32);
        }
        #pragma unroll
        for (int w = 0; w < 4; ++w)
            vx[w] = *(const float4*)(vg + (rowb + base + 128 * mm + 4 * jqV + w) * 64 + 4 * eqV);
    };
    auto stageConv = [&](int mm, const float4* kx, const float4* vx) {
        const int sl = mm & 1;
        float csA[4], snA[4];
        #pragma unroll
        for (int it = 0; it < 2; ++it) {
            int j = (tid + it * 512) >> 3;
            int t = 128 * mm + j;
            const float* x1p = (const float*)&kx[2 * it];
            const float* x2p = (const float*)&kx[2 * it + 1];
            f16x4 lo, hi;
            #pragma unroll
            for (int u = 0; u < 4; ++u) {
                float sn, cs;
                if (it == 0) {
                    __sincosf((float)t * invfK[u], &sn, &cs);
                    csA[u] = cs; snA[u] = sn;
                } else {
                    // t -> t+64 rotation (angle addition; 1 extra f32 rounding step)
                    cs = csA[u] * c64[u] - snA[u] * s64[u];
                    sn = snA[u] * c64[u] + csA[u] * s64[u];
                }
                lo[u] = (_Float16)(x1p[u] * cs - x2p[u] * sn);
                hi[u] = (_Float16)(x2p[u] * cs + x1p[u] * sn);
            }
            *(f16x4*)&Ks[sl][j][cbK]      = lo;
            *(f16x4*)&Ks[sl][j][cbK + 32] = hi;
        }
        #pragma unroll
        for (int u = 0; u < 4; ++u) {
            f16x4 o;
            o[0] = (_Float16)((const float*)&vx[0])[u];
            o[1] = (_Float16)((const float*)&vx[1])[u];
            o[2] = (_Float16)((const float*)&vx[2])[u];
            o[3] = (_Float16)((const float*)&vx[3])[u];
            *(f16x4*)&Vt[sl][4 * eqV + u][colbV] = o;
        }
    };
    auto stageFused = [&](int mm) {       // for stage(2): load+convert in one pass
        float4 kx[4], vx[4];
        stageLoad(mm, kx, vx);
        stageConv(mm, kx, vx);
    };

    // ---- Q: split load / RoPE ----
    auto loadQraw = [&](int wi, float4* qr) {
        const int tq = 128 * (wi + 1) + qrow;
        const float* p = qg + (rowb + base + tq) * 64 + 8 * g;
        qr[0] = *(const float4*)p;
        qr[1] = *(const float4*)(p + 4);
        qr[2] = *(const float4*)(p + 32);
        qr[3] = *(const float4*)(p + 36);
    };
    auto ropeQ = [&](int wi, const float4* qr, f16x8& qa0, f16x8& qa1) {
        const int tq = 128 * (wi + 1) + qrow;
        float ra[8] = {qr[0].x,qr[0].y,qr[0].z,qr[0].w,qr[1].x,qr[1].y,qr[1].z,qr[1].w};
        float rb[8] = {qr[2].x,qr[2].y,qr[2].z,qr[2].w,qr[3].x,qr[3].y,qr[3].z,qr[3].w};
        #pragma unroll
        for (int u = 0; u < 8; ++u) {
            float sn, cs; __sincosf((float)tq * invfQ[u], &sn, &cs);
            float a = ra[u] * QSCALE, b = rb[u] * QSCALE;
            qa0[u] = (_Float16)(a * cs - b * sn);
            qa1[u] = (_Float16)(b * cs + a * sn);
        }
    };

    // ---- compute one window (wi), flat softmax, fused exp+pack+PV ----
    auto computeWin = [&](int wi, f16x8 qa0, f16x8 qa1) {
        const bool skipFirst = (wp == 0 && wi == 0);  // padding half
        const int sl0 = wi & 1, sl1 = (wi + 1) & 1;
        const f32x4 CZERO = (f32x4){0.f, 0.f, 0.f, 0.f};

        f32x4 acc[16];
        #pragma unroll
        for (int jt = 0; jt < 16; ++jt) {
            const bool doit = (jt < 8) ? (!skipFirst) : ((jt - 8) <= wv);
            if (doit) {
                const int sl = (jt < 8) ? sl0 : sl1;
                const int row = (jt & 7) * 16 + c;
                f16x8 kb0 = *(const f16x8*)&Ks[sl][row][8 * g];
                f16x8 kb1 = *(const f16x8*)&Ks[sl][row][32 + 8 * g];
                acc[jt] = __builtin_amdgcn_mfma_f32_16x16x32_f16(kb0, qa0, CZERO, 0, 0, 0);
                acc[jt] = __builtin_amdgcn_mfma_f32_16x16x32_f16(kb1, qa1, acc[jt], 0, 0, 0);
            }
        }

        // mask (diag tile only) + max over computed tiles
        float mx = NEG;
        #pragma unroll
        for (int jt = 0; jt < 16; ++jt) {
            const bool doit = (jt < 8) ? (!skipFirst) : ((jt - 8) <= wv);
            if (doit) {
                if (jt >= 8 && jt == 8 + wv) {
                    #pragma unroll
                    for (int r = 0; r < 4; ++r)
                        if (4 * g + r > c) acc[jt][r] = NEG;
                }
                #pragma unroll
                for (int r = 0; r < 4; ++r) mx = fmaxf(mx, acc[jt][r]);
            }
        }
        mx = fmaxf(mx, __shfl_xor(mx, 16));
        mx = fmaxf(mx, __shfl_xor(mx, 32));

        // fused: per 32-key group, exp2 + pack ONE fragment + 4 PV MFMAs; s on the fly
        f32x4 accO[4];
        #pragma unroll
        for (int nt = 0; nt < 4; ++nt) accO[nt] = CZERO;

        float s = 0.f;
        #pragma unroll
        for (int st = 0; st < 8; ++st) {
            const bool grp = (st < 4) ? (!skipFirst) : ((2 * st - 8) <= wv);
            if (grp) {
                f16x8 pa;
                #pragma unroll
                for (int r = 0; r < 4; ++r) {
                    float p = EXP2F(acc[2 * st][r] - mx);     // masked -> 0
                    s += p;
                    pa[r] = (_Float16)p;
                }
                const bool oddOk = (st < 4) || ((2 * st - 7) <= wv);
                if (oddOk) {
                    #pragma unroll
                    for (int r = 0; r < 4; ++r) {
                        float p = EXP2F(acc[2 * st + 1][r] - mx);
                        s += p;
                        pa[4 + r] = (_Float16)p;
                    }
                } else {
                    #pragma unroll
                    for (int r = 0; r < 4; ++r) pa[4 + r] = (_Float16)0.f;
                }
                const int sl = (st < 4) ? sl0 : sl1;
                #pragma unroll
                for (int nt = 0; nt < 4; ++nt) {
                    f16x8 vb = *(const f16x8*)&Vt[sl][nt * 16 + c][(st & 3) * 32 + 8 * g];
                    accO[nt] = __builtin_amdgcn_mfma_f32_16x16x32_f16(pa, vb, accO[nt], 0, 0, 0);
                }
            }
        }
        s += __shfl_xor(s, 16);
        s += __shfl_xor(s, 32);

        // epilogue: 1/s (c-layout) -> row-layout, store
        float rcp = 1.0f / s;
        float rcpD[4];
        #pragma unroll
        for (int r = 0; r < 4; ++r)
            rcpD[r] = __shfl(rcp, (lane & 48) | (4 * g + r));

        float* op = outg + (rowb + base + 128 * (wi + 1) + wv * 16) * 64;
        #pragma unroll
        for (int nt = 0; nt < 4; ++nt)
            #pragma unroll
            for (int r = 0; r < 4; ++r)
                op[(size_t)(4 * g + r) * 64 + nt * 16 + c] = accO[nt][r] * rcpD[r];
    };

    // ---- schedule: issue ALL front loads (Q, K0, V0, K1, V1) -> convert both ->
    //      ropeQ(0) -> sync -> win0 -> Qraw(1) -> sync -> stage(2) fused ->
    //      ropeQ(1) -> sync -> win1 ----
    float4 qr[4];
    loadQraw(0, qr);
    float4 k0[4], v0[4], k1[4], v1[4];
    if (wp > 0) stageLoad(0, k0, v0);
    stageLoad(1, k1, v1);
    if (wp > 0) stageConv(0, k0, v0);
    stageConv(1, k1, v1);

    f16x8 qA, qB;
    ropeQ(0, qr, qA, qB);
    __syncthreads();
    computeWin(0, qA, qB);
    loadQraw(1, qr);                      // issue win1's Q before the barrier
    __syncthreads();                      // all reads of slot0 done
    stageFused(2);
    ropeQ(1, qr, qA, qB);
    __syncthreads();
    computeWin(1, qA, qB);
}

extern "C" void kernel_launch(void* const* d_in, const int* in_sizes, int n_in,
                              void* d_out, int out_size, void* d_ws, size_t ws_size,
                              hipStream_t stream) {
    (void)in_sizes; (void)n_in; (void)out_size; (void)d_ws; (void)ws_size;
    const float* q = (const float*)d_in[0];
    const float* k = (const float*)d_in[1];
    const float* v = (const float*)d_in[2];
    float* out = (float*)d_out;
    dim3 grid(16, 32);  // x = window-pair, y = batch
    la_kernel<<<grid, BDIM, 0, stream>>>(q, k, v, out);
}

// Round 23
// 32.683 us; speedup vs baseline: 1.0639x; 1.0502x over previous
//
#include <hip/hip_runtime.h>
#include <hip/hip_bf16.h>

#define BDIM 512

typedef __attribute__((ext_vector_type(8))) _Float16 f16x8;
typedef __attribute__((ext_vector_type(4))) _Float16 f16x4;
typedef __attribute__((ext_vector_type(4))) float f32x4;

// native v_exp_f32 computes 2^x; __exp2f doesn't exist in HIP
#define EXP2F(x) __builtin_amdgcn_exp2f(x)

// Local windowed attention with RoPE. b=32, n=4096, d=64, WINDOW=128, 1 backward window.
// FINAL = R20 (31.9us, best measured). ONE BLOCK PER WINDOW-PAIR (RoPE relative-
// position invariance -> middle K/V half shared; block-common origin, t in [0,384)).
// 3 halves in 2 rolling LDS slots (72.7KB, 2 blocks/CU, launch_bounds(512,4)).
// Techniques (each A/B-verified): front-staging load/convert split (all 20 float4
// in flight -> 2x MLP at kernel start), swapped QK^T via mfma(K,Q) (per-query stats
// in c-layout, accO in row-layout, 1/s shuffled c->row), permuted Vt columns (PV
// B-operand = one ds_read_b128), flat softmax over acc[16] (both halves resident),
// fused exp/pack/PV (s accumulated on the fly), exp2-domain scores (log2e folded
// into Q scale), tile-granular causal skips ((jt-8) <= wv), diag mask 4g+r > c,
// Q loads issued before staging.
// Falsified axes (do not revisit): occupancy up (R15/16) & down (R19), barrier-domain
// count (R11/R19), reg-prefetch across compute (R10/R14), K/V LDS aliasing (R3),
// RoPE table (R7), XCD swizzle (R21), sincos recurrence (R22 - register cost > VALU
// savings). Spill sentinel: WRITE_SIZE == output 32.8MB.
__global__ __launch_bounds__(512, 4)
void la_kernel(const float* __restrict__ qg, const float* __restrict__ kg,
               const float* __restrict__ vg, float* __restrict__ outg)
{
    __shared__ _Float16 Ks[2][128][72];   // 36864 B
    __shared__ _Float16 Vt[2][64][140];   // 35840 B   total 72704 B

    const int wp = blockIdx.x, bb = blockIdx.y;
    const int tid = threadIdx.x;
    const int wv = tid >> 6, lane = tid & 63, g = lane >> 4, c = lane & 15;
    const int base = 256 * wp - 128;      // phys row of t=0 (block-common origin)
    const float NEG = -3.0e38f;
    const float NLT32 = -0.28782313662425572f;   // -ln(10000)/32
    const float QSCALE = 0.125f * 1.4426950408889634f;  // d^-0.5 * log2(e)
    const size_t rowb = (size_t)bb * 4096;

    // hoisted inverse frequencies
    const int cbK = (tid & 7) << 2;
    float invfK[4];
    #pragma unroll
    for (int u = 0; u < 4; ++u) invfK[u] = __expf((float)(cbK + u) * NLT32);
    float invfQ[8];
    #pragma unroll
    for (int u = 0; u < 8; ++u) invfQ[u] = __expf((float)(8 * g + u) * NLT32);

    const int jqV = tid >> 4, eqV = tid & 15;
    const int colbV = ((jqV & 24) << 2) + 8 * (jqV & 3) + 4 * ((jqV >> 2) & 1);

    const int qrow = wv * 16 + c;

    // ---- staging split: raw loads / convert+LDS-write ----
    auto stageLoad = [&](int mm, float4* kx, float4* vx) {
        #pragma unroll
        for (int it = 0; it < 2; ++it) {
            int j = (tid + it * 512) >> 3;         // 0..127
            const float* p = kg + (rowb + base + 128 * mm + j) * 64 + cbK;
            kx[2 * it]     = *(const float4*)p;
            kx[2 * it + 1] = *(const float4*)(p + 32);
        }
        #pragma unroll
        for (int w = 0; w < 4; ++w)
            vx[w] = *(const float4*)(vg + (rowb + base + 128 * mm + 4 * jqV + w) * 64 + 4 * eqV);
    };
    auto stageConv = [&](int mm, const float4* kx, const float4* vx) {
        const int sl = mm & 1;
        #pragma unroll
        for (int it = 0; it < 2; ++it) {
            int j = (tid + it * 512) >> 3;
            int t = 128 * mm + j;
            const float* x1p = (const float*)&kx[2 * it];
            const float* x2p = (const float*)&kx[2 * it + 1];
            f16x4 lo, hi;
            #pragma unroll
            for (int u = 0; u < 4; ++u) {
                float sn, cs; __sincosf((float)t * invfK[u], &sn, &cs);
                lo[u] = (_Float16)(x1p[u] * cs - x2p[u] * sn);
                hi[u] = (_Float16)(x2p[u] * cs + x1p[u] * sn);
            }
            *(f16x4*)&Ks[sl][j][cbK]      = lo;
            *(f16x4*)&Ks[sl][j][cbK + 32] = hi;
        }
        #pragma unroll
        for (int u = 0; u < 4; ++u) {
            f16x4 o;
            o[0] = (_Float16)((const float*)&vx[0])[u];
            o[1] = (_Float16)((const float*)&vx[1])[u];
            o[2] = (_Float16)((const float*)&vx[2])[u];
            o[3] = (_Float16)((const float*)&vx[3])[u];
            *(f16x4*)&Vt[sl][4 * eqV + u][colbV] = o;
        }
    };
    auto stageFused = [&](int mm) {       // for stage(2): load+convert in one pass
        float4 kx[4], vx[4];
        stageLoad(mm, kx, vx);
        stageConv(mm, kx, vx);
    };

    // ---- Q: split load / RoPE ----
    auto loadQraw = [&](int wi, float4* qr) {
        const int tq = 128 * (wi + 1) + qrow;
        const float* p = qg + (rowb + base + tq) * 64 + 8 * g;
        qr[0] = *(const float4*)p;
        qr[1] = *(const float4*)(p + 4);
        qr[2] = *(const float4*)(p + 32);
        qr[3] = *(const float4*)(p + 36);
    };
    auto ropeQ = [&](int wi, const float4* qr, f16x8& qa0, f16x8& qa1) {
        const int tq = 128 * (wi + 1) + qrow;
        float ra[8] = {qr[0].x,qr[0].y,qr[0].z,qr[0].w,qr[1].x,qr[1].y,qr[1].z,qr[1].w};
        float rb[8] = {qr[2].x,qr[2].y,qr[2].z,qr[2].w,qr[3].x,qr[3].y,qr[3].z,qr[3].w};
        #pragma unroll
        for (int u = 0; u < 8; ++u) {
            float sn, cs; __sincosf((float)tq * invfQ[u], &sn, &cs);
            float a = ra[u] * QSCALE, b = rb[u] * QSCALE;
            qa0[u] = (_Float16)(a * cs - b * sn);
            qa1[u] = (_Float16)(b * cs + a * sn);
        }
    };

    // ---- compute one window (wi), flat softmax, fused exp+pack+PV ----
    auto computeWin = [&](int wi, f16x8 qa0, f16x8 qa1) {
        const bool skipFirst = (wp == 0 && wi == 0);  // padding half
        const int sl0 = wi & 1, sl1 = (wi + 1) & 1;
        const f32x4 CZERO = (f32x4){0.f, 0.f, 0.f, 0.f};

        f32x4 acc[16];
        #pragma unroll
        for (int jt = 0; jt < 16; ++jt) {
            const bool doit = (jt < 8) ? (!skipFirst) : ((jt - 8) <= wv);
            if (doit) {
                const int sl = (jt < 8) ? sl0 : sl1;
                const int row = (jt & 7) * 16 + c;
                f16x8 kb0 = *(const f16x8*)&Ks[sl][row][8 * g];
                f16x8 kb1 = *(const f16x8*)&Ks[sl][row][32 + 8 * g];
                acc[jt] = __builtin_amdgcn_mfma_f32_16x16x32_f16(kb0, qa0, CZERO, 0, 0, 0);
                acc[jt] = __builtin_amdgcn_mfma_f32_16x16x32_f16(kb1, qa1, acc[jt], 0, 0, 0);
            }
        }

        // mask (diag tile only) + max over computed tiles
        float mx = NEG;
        #pragma unroll
        for (int jt = 0; jt < 16; ++jt) {
            const bool doit = (jt < 8) ? (!skipFirst) : ((jt - 8) <= wv);
            if (doit) {
                if (jt >= 8 && jt == 8 + wv) {
                    #pragma unroll
                    for (int r = 0; r < 4; ++r)
                        if (4 * g + r > c) acc[jt][r] = NEG;
                }
                #pragma unroll
                for (int r = 0; r < 4; ++r) mx = fmaxf(mx, acc[jt][r]);
            }
        }
        mx = fmaxf(mx, __shfl_xor(mx, 16));
        mx = fmaxf(mx, __shfl_xor(mx, 32));

        // fused: per 32-key group, exp2 + pack ONE fragment + 4 PV MFMAs; s on the fly
        f32x4 accO[4];
        #pragma unroll
        for (int nt = 0; nt < 4; ++nt) accO[nt] = CZERO;

        float s = 0.f;
        #pragma unroll
        for (int st = 0; st < 8; ++st) {
            const bool grp = (st < 4) ? (!skipFirst) : ((2 * st - 8) <= wv);
            if (grp) {
                f16x8 pa;
                #pragma unroll
                for (int r = 0; r < 4; ++r) {
                    float p = EXP2F(acc[2 * st][r] - mx);     // masked -> 0
                    s += p;
                    pa[r] = (_Float16)p;
                }
                const bool oddOk = (st < 4) || ((2 * st - 7) <= wv);
                if (oddOk) {
                    #pragma unroll
                    for (int r = 0; r < 4; ++r) {
                        float p = EXP2F(acc[2 * st + 1][r] - mx);
                        s += p;
                        pa[4 + r] = (_Float16)p;
                    }
                } else {
                    #pragma unroll
                    for (int r = 0; r < 4; ++r) pa[4 + r] = (_Float16)0.f;
                }
                const int sl = (st < 4) ? sl0 : sl1;
                #pragma unroll
                for (int nt = 0; nt < 4; ++nt) {
                    f16x8 vb = *(const f16x8*)&Vt[sl][nt * 16 + c][(st & 3) * 32 + 8 * g];
                    accO[nt] = __builtin_amdgcn_mfma_f32_16x16x32_f16(pa, vb, accO[nt], 0, 0, 0);
                }
            }
        }
        s += __shfl_xor(s, 16);
        s += __shfl_xor(s, 32);

        // epilogue: 1/s (c-layout) -> row-layout, store
        float rcp = 1.0f / s;
        float rcpD[4];
        #pragma unroll
        for (int r = 0; r < 4; ++r)
            rcpD[r] = __shfl(rcp, (lane & 48) | (4 * g + r));

        float* op = outg + (rowb + base + 128 * (wi + 1) + wv * 16) * 64;
        #pragma unroll
        for (int nt = 0; nt < 4; ++nt)
            #pragma unroll
            for (int r = 0; r < 4; ++r)
                op[(size_t)(4 * g + r) * 64 + nt * 16 + c] = accO[nt][r] * rcpD[r];
    };

    // ---- schedule: issue ALL front loads (Q, K0, V0, K1, V1) -> convert both ->
    //      ropeQ(0) -> sync -> win0 -> Qraw(1) -> sync -> stage(2) fused ->
    //      ropeQ(1) -> sync -> win1 ----
    float4 qr[4];
    loadQraw(0, qr);
    float4 k0[4], v0[4], k1[4], v1[4];
    if (wp > 0) stageLoad(0, k0, v0);
    stageLoad(1, k1, v1);
    if (wp > 0) stageConv(0, k0, v0);
    stageConv(1, k1, v1);

    f16x8 qA, qB;
    ropeQ(0, qr, qA, qB);
    __syncthreads();
    computeWin(0, qA, qB);
    loadQraw(1, qr);                      // issue win1's Q before the barrier
    __syncthreads();                      // all reads of slot0 done
    stageFused(2);
    ropeQ(1, qr, qA, qB);
    __syncthreads();
    computeWin(1, qA, qB);
}

extern "C" void kernel_launch(void* const* d_in, const int* in_sizes, int n_in,
                              void* d_out, int out_size, void* d_ws, size_t ws_size,
                              hipStream_t stream) {
    (void)in_sizes; (void)n_in; (void)out_size; (void)d_ws; (void)ws_size;
    const float* q = (const float*)d_in[0];
    const float* k = (const float*)d_in[1];
    const float* v = (const float*)d_in[2];
    float* out = (float*)d_out;
    dim3 grid(16, 32);  // x = window-pair, y = batch
    la_kernel<<<grid, BDIM, 0, stream>>>(q, k, v, out);
}